// Round 3
// baseline (81.483 us; speedup 1.0000x reference)
//
#include <hip/hip_runtime.h>

// B=128, H=W=28 (HW=784), C=128.
// ref: per-(b,c) spatial argmax of x -> gather t_p[c, h*, w*] (a [28,28] tile)
// -> outputs (relu(x*t), x, t) each [B,H,W,C], concatenated in d_out.
//
// Single fused kernel: grid (2 halves, B). Each block redundantly computes
// the full argmax for its b (block-local, no cross-block dep; the 2x x-read
// is L3-absorbed), then writes its 392-s half of all three outputs.

constexpr int HWc = 784, Cc = 128, Bc = 128;

typedef float f4 __attribute__((ext_vector_type(4)));
typedef int i4 __attribute__((ext_vector_type(4)));

__device__ inline void nt_store(float* p, f4 v) {
  __builtin_nontemporal_store(v, (f4*)p);
}
__device__ inline f4 nt_load(const float* p) {
  return __builtin_nontemporal_load((const f4*)p);
}

__global__ __launch_bounds__(1024) void fused_kernel(
    const float* __restrict__ x, const float* __restrict__ tp,
    float* __restrict__ out) {
  int half = blockIdx.x;
  int b = blockIdx.y;
  int t = threadIdx.x;
  int c4 = t & 31;   // channel group: owns channels 4*c4 .. 4*c4+3
  int g = t >> 5;    // 0..31: s-partition (phase 1) / s4-group (phase 3)
  int ch = c4 << 2;

  const size_t plane = (size_t)HWc * Cc;  // 100352
  size_t bplane = (size_t)b * plane;

  __shared__ float smax[32][Cc];  // 16 KB
  __shared__ int sidx[32][Cc];    // 16 KB
  __shared__ int tbase[Cc];       // per-channel t_p row base (floats, <2^31)

  // ---- phase 1: partial argmax over full 784 s, 32 parts x <=25 s ----
  // float4 over c; strict '>' in ascending s preserves first-max semantics.
  {
    int s0 = g * 25;
    int send = (s0 + 25 < HWc) ? (s0 + 25) : HWc;  // part 31: 9 iters
    const f4* p = (const f4*)(x + bplane + (size_t)s0 * Cc + ch);
    f4 best = {-3.4e38f, -3.4e38f, -3.4e38f, -3.4e38f};
    i4 bi = {s0, s0, s0, s0};
    for (int s = s0; s < send; ++s) {
      f4 v = *p;
      p += Cc / 4;
      if (v[0] > best[0]) { best[0] = v[0]; bi[0] = s; }
      if (v[1] > best[1]) { best[1] = v[1]; bi[1] = s; }
      if (v[2] > best[2]) { best[2] = v[2]; bi[2] = s; }
      if (v[3] > best[3]) { best[3] = v[3]; bi[3] = s; }
    }
    *(f4*)&smax[g][ch] = best;
    *(i4*)&sidx[g][ch] = bi;
  }
  __syncthreads();

  // ---- phase 2: reduce 32 partials per channel (ascending p, strict >) ----
  if (t < Cc) {
    float m = smax[0][t];
    int mi = sidx[0][t];
#pragma unroll
    for (int p = 1; p < 32; ++p) {
      float v = smax[p][t];
      if (v > m) { m = v; mi = sidx[p][t]; }
    }
    tbase[t] = (t * HWc + mi) * HWc;
  }
  __syncthreads();

  // ---- phase 3: outputs for this half's 392-s range ----
  // 98 s4-groups x 32 c4-groups; thread does 4s x 4c register tile.
  const float* r0 = tp + tbase[ch + 0];
  const float* r1 = tp + tbase[ch + 1];
  const float* r2 = tp + tbase[ch + 2];
  const float* r3 = tp + tbase[ch + 3];

  float* om = out;
  float* ox = out + (size_t)Bc * plane;
  float* ot = out + 2 * (size_t)Bc * plane;
  int sbase = half * 392;

  for (int k = 0; k < 4; ++k) {
    int idx = g + (k << 5);
    if (idx < 98) {
      int s0 = sbase + (idx << 2);
      size_t off = bplane + (size_t)s0 * Cc + ch;
      const float* xp = x + off;

      f4 xv0 = *(const f4*)(xp);            // x: L2-hot from phase 1
      f4 xv1 = *(const f4*)(xp + Cc);
      f4 xv2 = *(const f4*)(xp + 2 * Cc);
      f4 xv3 = *(const f4*)(xp + 3 * Cc);
      f4 tv0 = nt_load(r0 + s0);            // t_p: read-once, don't cache
      f4 tv1 = nt_load(r1 + s0);
      f4 tv2 = nt_load(r2 + s0);
      f4 tv3 = nt_load(r3 + s0);

      float* omp = om + off;
      float* oxp = ox + off;
      float* otp = ot + off;

#pragma unroll
      for (int i = 0; i < 4; ++i) {
        f4 xvi = (i == 0) ? xv0 : (i == 1) ? xv1 : (i == 2) ? xv2 : xv3;
        f4 tcol = {tv0[i], tv1[i], tv2[i], tv3[i]};
        f4 mv;
        mv[0] = fmaxf(xvi[0] * tcol[0], 0.f);
        mv[1] = fmaxf(xvi[1] * tcol[1], 0.f);
        mv[2] = fmaxf(xvi[2] * tcol[2], 0.f);
        mv[3] = fmaxf(xvi[3] * tcol[3], 0.f);
        nt_store(omp + i * Cc, mv);
        nt_store(oxp + i * Cc, xvi);
        nt_store(otp + i * Cc, tcol);
      }
    }
  }
}

extern "C" void kernel_launch(void* const* d_in, const int* in_sizes, int n_in,
                              void* d_out, int out_size, void* d_ws,
                              size_t ws_size, hipStream_t stream) {
  const float* x = (const float*)d_in[0];
  const float* tp = (const float*)d_in[1];
  float* out = (float*)d_out;
  fused_kernel<<<dim3(2, Bc), 1024, 0, stream>>>(x, tp, out);
}

// Round 4
// 56.948 us; speedup vs baseline: 1.4308x; 1.4308x over previous
//
#include <hip/hip_runtime.h>

// B=128, H=W=28 (HW=784), C=128.
// ref: per-(b,c) spatial argmax of x -> gather t_p[c, h*, w*] (a [28,28] tile)
// -> outputs (relu(x*t), x, t) each [B,H,W,C], concatenated in d_out.
//
// R4 structure: two kernels.
//  K1: argmax partials (2 spatial halves per b) + writes the ox slab while x
//      is in registers (balances the read-only window with write traffic).
//  K2: finalize argmax, write om (relu(x*t)) and ot (t) slabs. High TLP.

constexpr int HWc = 784, Cc = 128, Bc = 128;

typedef float f4 __attribute__((ext_vector_type(4)));
typedef int i4 __attribute__((ext_vector_type(4)));

__device__ inline void nt_store(float* p, f4 v) {
  __builtin_nontemporal_store(v, (f4*)p);
}

// ---------------------------------------------------------------------------
// K1: grid (2, B), 512 threads. Thread: c4 = t&31 (channels 4c4..4c4+3),
// part = t>>5 (16 parts; 15x25 + 1x17 s). Reads x (float4, coalesced),
// updates per-channel argmax, nt-stores the x copy to ox.
// Strict '>' in ascending-s order preserves JAX first-max tie semantics.
// ---------------------------------------------------------------------------
__global__ __launch_bounds__(512) void argmax_copy_kernel(
    const float* __restrict__ x, float* __restrict__ ox,
    float* __restrict__ pmax, int* __restrict__ pidx) {
  int chunk = blockIdx.x;  // 0..1
  int b = blockIdx.y;
  int t = threadIdx.x;
  int c4 = t & 31;
  int part = t >> 5;  // 0..15
  int ch = c4 << 2;

  int cbase = chunk * 392;
  int s0 = cbase + part * 25;
  int send = s0 + 25;
  if (send > cbase + 392) send = cbase + 392;  // part 15: 17 iters

  const size_t plane = (size_t)HWc * Cc;
  const float* xp = x + (size_t)b * plane + ch;
  float* oxp = ox + (size_t)b * plane + ch;

  f4 best = {-3.4e38f, -3.4e38f, -3.4e38f, -3.4e38f};
  i4 bi = {s0, s0, s0, s0};
  for (int s = s0; s < send; ++s) {
    f4 v = *(const f4*)(xp + (size_t)s * Cc);
    nt_store(oxp + (size_t)s * Cc, v);
    if (v[0] > best[0]) { best[0] = v[0]; bi[0] = s; }
    if (v[1] > best[1]) { best[1] = v[1]; bi[1] = s; }
    if (v[2] > best[2]) { best[2] = v[2]; bi[2] = s; }
    if (v[3] > best[3]) { best[3] = v[3]; bi[3] = s; }
  }

  __shared__ float smax[16][Cc];
  __shared__ int sidx[16][Cc];
  *(f4*)&smax[part][ch] = best;
  *(i4*)&sidx[part][ch] = bi;
  __syncthreads();

  if (t < Cc) {
    float m = smax[0][t];
    int mi = sidx[0][t];
#pragma unroll
    for (int p = 1; p < 16; ++p) {
      float v = smax[p][t];
      if (v > m) { m = v; mi = sidx[p][t]; }  // strict >: earliest s wins
    }
    int o = (b * 2 + chunk) * Cc + t;
    pmax[o] = m;
    pidx[o] = mi;
  }
}

// ---------------------------------------------------------------------------
// K2: finalize argmax (2 partials), write om and ot.
// grid (14, B), 256 threads: c4 = t&31, u = t>>5 (0..7), k = 0..1,
// idx = u + 8k < 14 (guard is wave-uniform). 4s x 4c register tile:
// 4 float4 x loads (L3-hot), 4 float4 t loads along s (L2-coalesced),
// register transpose, 8 float4 nt stores.
// ---------------------------------------------------------------------------
__global__ __launch_bounds__(256) void out_kernel(
    const float* __restrict__ x, const float* __restrict__ tp,
    const float* __restrict__ pmax, const int* __restrict__ pidx,
    float* __restrict__ out) {
  int b = blockIdx.y;
  int t = threadIdx.x;

  __shared__ int tbase[Cc];  // per-channel t_p row base in floats (<2^31)
  if (t < Cc) {
    int base = b * 2 * Cc + t;
    float m = pmax[base];
    int mi = pidx[base];
    float v = pmax[base + Cc];
    if (v > m) { m = v; mi = pidx[base + Cc]; }
    tbase[t] = (t * HWc + mi) * HWc;
  }
  __syncthreads();

  int c4 = t & 31;
  int u = t >> 5;
  int ch = c4 << 2;

  const float* r0 = tp + tbase[ch + 0];
  const float* r1 = tp + tbase[ch + 1];
  const float* r2 = tp + tbase[ch + 2];
  const float* r3 = tp + tbase[ch + 3];

  const size_t plane = (size_t)HWc * Cc;
  size_t bplane = (size_t)b * plane;
  float* om = out;                           // relu(x*t)
  float* ot = out + 2 * (size_t)Bc * plane;  // templates (ox written by K1)
  int sb = blockIdx.x * 56;

#pragma unroll
  for (int k = 0; k < 2; ++k) {
    int idx = u + (k << 3);
    if (idx < 14) {
      int s0 = sb + (idx << 2);
      size_t off = bplane + (size_t)s0 * Cc + ch;
      const float* xp = x + off;

      f4 xv0 = *(const f4*)(xp);
      f4 xv1 = *(const f4*)(xp + Cc);
      f4 xv2 = *(const f4*)(xp + 2 * Cc);
      f4 xv3 = *(const f4*)(xp + 3 * Cc);
      f4 tv0 = *(const f4*)(r0 + s0);
      f4 tv1 = *(const f4*)(r1 + s0);
      f4 tv2 = *(const f4*)(r2 + s0);
      f4 tv3 = *(const f4*)(r3 + s0);

      float* omp = om + off;
      float* otp = ot + off;

#pragma unroll
      for (int i = 0; i < 4; ++i) {
        f4 xvi = (i == 0) ? xv0 : (i == 1) ? xv1 : (i == 2) ? xv2 : xv3;
        f4 tcol = {tv0[i], tv1[i], tv2[i], tv3[i]};
        f4 mv;
        mv[0] = fmaxf(xvi[0] * tcol[0], 0.f);
        mv[1] = fmaxf(xvi[1] * tcol[1], 0.f);
        mv[2] = fmaxf(xvi[2] * tcol[2], 0.f);
        mv[3] = fmaxf(xvi[3] * tcol[3], 0.f);
        nt_store(omp + i * Cc, mv);
        nt_store(otp + i * Cc, tcol);
      }
    }
  }
}

extern "C" void kernel_launch(void* const* d_in, const int* in_sizes, int n_in,
                              void* d_out, int out_size, void* d_ws,
                              size_t ws_size, hipStream_t stream) {
  const float* x = (const float*)d_in[0];
  const float* tp = (const float*)d_in[1];
  float* out = (float*)d_out;
  float* ox = out + (size_t)Bc * HWc * Cc;  // slab 1: x copy, written by K1

  // workspace: pmax[B*2*C] floats + pidx[B*2*C] ints = 256 KB
  float* pmax = (float*)d_ws;
  int* pidx = (int*)((char*)d_ws + (size_t)Bc * 2 * Cc * sizeof(float));

  argmax_copy_kernel<<<dim3(2, Bc), 512, 0, stream>>>(x, ox, pmax, pidx);
  out_kernel<<<dim3(14, Bc), 256, 0, stream>>>(x, tp, pmax, pidx, out);
}